// Round 4
// baseline (273.381 us; speedup 1.0000x reference)
//
#include <hip/hip_runtime.h>
#include <float.h>

#define NUM_Q 8192
#define NUM_P 4096   // 1024 float4 per row -> 16 float4 per lane per wave

// One WAVE (64 lanes) per row. No __syncthreads, no LDS.
// Each lane: 16x float4 of pred (64 values) held in registers; y compressed
// to a 64-bit mask (2 VGPRs) as it arrives. Row min + hinge sum via
// 6-step shuffle butterflies. Per-row result -> ws[row]; tiny second kernel
// reduces the 8192 partials.
__global__ __launch_bounds__(256, 4)
void mmrl_kernel(const float* __restrict__ pred,
                 const int* __restrict__ y,
                 float* __restrict__ ws) {
    const int lane = threadIdx.x & 63;
    const int row  = blockIdx.x * (256 >> 6) + (threadIdx.x >> 6);  // wave id == row

    const float4* prow = reinterpret_cast<const float4*>(pred + (size_t)row * NUM_P);
    const int4*   yrow = reinterpret_cast<const int4*>(y + (size_t)row * NUM_P);

    // ---- issue all pred loads (16 x 1KB coalesced per wave) ----
    float4 pv[16];
#pragma unroll
    for (int i = 0; i < 16; ++i) pv[i] = prow[lane + 64 * i];

    // ---- y -> 64-bit relevance mask per lane (two batches of 8 int4) ----
    unsigned int m0 = 0u, m1 = 0u;
    {
        int4 ya[8];
#pragma unroll
        for (int i = 0; i < 8; ++i) ya[i] = yrow[lane + 64 * i];
#pragma unroll
        for (int i = 0; i < 8; ++i) {
            unsigned int b = (unsigned int)(ya[i].x == 1)
                           | ((unsigned int)(ya[i].y == 1) << 1)
                           | ((unsigned int)(ya[i].z == 1) << 2)
                           | ((unsigned int)(ya[i].w == 1) << 3);
            m0 |= b << (4 * i);
        }
#pragma unroll
        for (int i = 0; i < 8; ++i) ya[i] = yrow[lane + 64 * (8 + i)];
#pragma unroll
        for (int i = 0; i < 8; ++i) {
            unsigned int b = (unsigned int)(ya[i].x == 1)
                           | ((unsigned int)(ya[i].y == 1) << 1)
                           | ((unsigned int)(ya[i].z == 1) << 2)
                           | ((unsigned int)(ya[i].w == 1) << 3);
            m1 |= b << (4 * i);
        }
    }

    // ---- Phase 1: masked min (relevant entries only) ----
    float lmin = FLT_MAX;
#pragma unroll
    for (int i = 0; i < 16; ++i) {
        const unsigned int m = (i < 8) ? (m0 >> (4 * i)) : (m1 >> (4 * (i - 8)));
        lmin = fminf(lmin, (m & 1u) ? pv[i].x : FLT_MAX);
        lmin = fminf(lmin, (m & 2u) ? pv[i].y : FLT_MAX);
        lmin = fminf(lmin, (m & 4u) ? pv[i].z : FLT_MAX);
        lmin = fminf(lmin, (m & 8u) ? pv[i].w : FLT_MAX);
    }
#pragma unroll
    for (int off = 32; off > 0; off >>= 1)
        lmin = fminf(lmin, __shfl_xor(lmin, off));
    // all lanes now hold the row min

    // ---- Phase 2: hinge sum over non-relevant entries ----
    float lsum = 0.0f;
#pragma unroll
    for (int i = 0; i < 16; ++i) {
        const unsigned int m = (i < 8) ? (m0 >> (4 * i)) : (m1 >> (4 * (i - 8)));
        lsum += (m & 1u) ? 0.0f : fmaxf(pv[i].x - lmin, 0.0f);
        lsum += (m & 2u) ? 0.0f : fmaxf(pv[i].y - lmin, 0.0f);
        lsum += (m & 4u) ? 0.0f : fmaxf(pv[i].z - lmin, 0.0f);
        lsum += (m & 8u) ? 0.0f : fmaxf(pv[i].w - lmin, 0.0f);
    }
#pragma unroll
    for (int off = 32; off > 0; off >>= 1)
        lsum += __shfl_xor(lsum, off);

    if (lane == 0) ws[row] = lsum;
}

// Single-block reduction over the 8192 per-row partials.
__global__ __launch_bounds__(256)
void mmrl_reduce_kernel(const float* __restrict__ partial,
                        float* __restrict__ out) {
    const int t = threadIdx.x;
    const float4* p4 = reinterpret_cast<const float4*>(partial);
    float s = 0.0f;
#pragma unroll
    for (int i = 0; i < 8; ++i) {  // 256 threads * 8 float4 = 8192 floats
        float4 v = p4[t + 256 * i];
        s += (v.x + v.y) + (v.z + v.w);
    }
#pragma unroll
    for (int off = 32; off > 0; off >>= 1)
        s += __shfl_xor(s, off);

    __shared__ float ss[4];
    if ((t & 63) == 0) ss[t >> 6] = s;
    __syncthreads();

    if (t == 0) {
        const float total = (ss[0] + ss[1]) + (ss[2] + ss[3]);
        // mean over Q*P = 2^25 — exact power-of-two scale
        out[0] = total * (1.0f / ((float)NUM_Q * (float)NUM_P));
    }
}

extern "C" void kernel_launch(void* const* d_in, const int* in_sizes, int n_in,
                              void* d_out, int out_size, void* d_ws, size_t ws_size,
                              hipStream_t stream) {
    const float* pred = (const float*)d_in[0];
    const int*   y    = (const int*)d_in[1];
    float* out = (float*)d_out;
    float* ws  = (float*)d_ws;  // 8192 floats = 32 KB scratch

    mmrl_kernel<<<NUM_Q / 4, 256, 0, stream>>>(pred, y, ws);  // 4 waves/block, 1 row/wave
    mmrl_reduce_kernel<<<1, 256, 0, stream>>>(ws, out);
}

// Round 5
// 249.503 us; speedup vs baseline: 1.0957x; 1.0957x over previous
//
#include <hip/hip_runtime.h>
#include <float.h>

#define NUM_Q 8192
#define NUM_P 4096

typedef float  f32x4 __attribute__((ext_vector_type(4)));
typedef int    i32x4 __attribute__((ext_vector_type(4)));

// One block (256 threads = 4 waves) per row — best structure so far (R1, 95us).
// Changes vs R1:
//  * non-temporal loads (nt) for pred and y — test whether the ~2.8 TB/s
//    effective read rate is an L2/L3 allocation-path cap that NT bypasses.
//  * y loaded BEFORE pred: mask computation only waits on the y loads
//    (vmcnt covers issue order), overlapping mask VALU with pred in flight.
//  * select-form masked min (no divergent branches).
__global__ __launch_bounds__(256)
void mmrl_kernel(const float* __restrict__ pred,
                 const int* __restrict__ y,
                 float* __restrict__ ws) {
    const int row = blockIdx.x;
    const int t = threadIdx.x;

    const f32x4* prow = reinterpret_cast<const f32x4*>(pred + (size_t)row * NUM_P);
    const i32x4* yrow = reinterpret_cast<const i32x4*>(y + (size_t)row * NUM_P);

    // ---- issue y first, then pred (16B/lane coalesced, nt) ----
    i32x4 yv[4];
#pragma unroll
    for (int i = 0; i < 4; ++i) yv[i] = __builtin_nontemporal_load(&yrow[t + 256 * i]);
    f32x4 pv[4];
#pragma unroll
    for (int i = 0; i < 4; ++i) pv[i] = __builtin_nontemporal_load(&prow[t + 256 * i]);

    // ---- relevance mask (waits only on y loads) ----
    unsigned int m = 0u;
#pragma unroll
    for (int i = 0; i < 4; ++i) {
        m |= ((unsigned int)(yv[i].x == 1)      ) << (4 * i);
        m |= ((unsigned int)(yv[i].y == 1) << 1 ) << (4 * i);
        m |= ((unsigned int)(yv[i].z == 1) << 2 ) << (4 * i);
        m |= ((unsigned int)(yv[i].w == 1) << 3 ) << (4 * i);
    }

    // ---- Phase 1: min over relevant (select form) ----
    float lmin = FLT_MAX;
#pragma unroll
    for (int i = 0; i < 4; ++i) {
        lmin = fminf(lmin, (m & (1u << (4 * i)))     ? pv[i].x : FLT_MAX);
        lmin = fminf(lmin, (m & (2u << (4 * i)))     ? pv[i].y : FLT_MAX);
        lmin = fminf(lmin, (m & (4u << (4 * i)))     ? pv[i].z : FLT_MAX);
        lmin = fminf(lmin, (m & (8u << (4 * i)))     ? pv[i].w : FLT_MAX);
    }
#pragma unroll
    for (int off = 32; off > 0; off >>= 1)
        lmin = fminf(lmin, __shfl_xor(lmin, off));

    __shared__ float smin[4];
    __shared__ float ssum[4];
    const int wave = t >> 6;
    if ((t & 63) == 0) smin[wave] = lmin;
    __syncthreads();
    const float rmin = fminf(fminf(smin[0], smin[1]), fminf(smin[2], smin[3]));

    // ---- Phase 2: hinge sum over non-relevant ----
    float lsum = 0.0f;
#pragma unroll
    for (int i = 0; i < 4; ++i) {
        lsum += (m & (1u << (4 * i))) ? 0.0f : fmaxf(pv[i].x - rmin, 0.0f);
        lsum += (m & (2u << (4 * i))) ? 0.0f : fmaxf(pv[i].y - rmin, 0.0f);
        lsum += (m & (4u << (4 * i))) ? 0.0f : fmaxf(pv[i].z - rmin, 0.0f);
        lsum += (m & (8u << (4 * i))) ? 0.0f : fmaxf(pv[i].w - rmin, 0.0f);
    }
#pragma unroll
    for (int off = 32; off > 0; off >>= 1)
        lsum += __shfl_xor(lsum, off);

    if ((t & 63) == 0) ssum[wave] = lsum;
    __syncthreads();

    if (t == 0) {
        ws[row] = (ssum[0] + ssum[1]) + (ssum[2] + ssum[3]);
    }
}

// Single-block reduction over the 8192 per-row partials.
__global__ __launch_bounds__(256)
void mmrl_reduce_kernel(const float* __restrict__ partial,
                        float* __restrict__ out) {
    const int t = threadIdx.x;
    const f32x4* p4 = reinterpret_cast<const f32x4*>(partial);
    float s = 0.0f;
#pragma unroll
    for (int i = 0; i < 8; ++i) {  // 256 threads * 8 float4 = 8192 floats
        f32x4 v = p4[t + 256 * i];
        s += (v.x + v.y) + (v.z + v.w);
    }
#pragma unroll
    for (int off = 32; off > 0; off >>= 1)
        s += __shfl_xor(s, off);

    __shared__ float ss[4];
    if ((t & 63) == 0) ss[t >> 6] = s;
    __syncthreads();

    if (t == 0) {
        const float total = (ss[0] + ss[1]) + (ss[2] + ss[3]);
        // mean over Q*P = 2^25 — exact power-of-two scale
        out[0] = total * (1.0f / ((float)NUM_Q * (float)NUM_P));
    }
}

extern "C" void kernel_launch(void* const* d_in, const int* in_sizes, int n_in,
                              void* d_out, int out_size, void* d_ws, size_t ws_size,
                              hipStream_t stream) {
    const float* pred = (const float*)d_in[0];
    const int*   y    = (const int*)d_in[1];
    float* out = (float*)d_out;
    float* ws  = (float*)d_ws;  // 8192 floats = 32 KB scratch

    mmrl_kernel<<<NUM_Q, 256, 0, stream>>>(pred, y, ws);
    mmrl_reduce_kernel<<<1, 256, 0, stream>>>(ws, out);
}